// Round 1
// baseline (344.089 us; speedup 1.0000x reference)
//
#include <hip/hip_runtime.h>
#include <hip/hip_bf16.h>
#include <stdint.h>

#define B_DIM 64
#define S_DIM 512
#define K_DIM 1024   // F_IN
#define N_DIM 1024   // F_OUT
#define M_DIM (B_DIM * S_DIM)  // 32768
#define N_TILES 256            // M_DIM / 128 (m-tiles; 128 rows = 128 consecutive s)

typedef __attribute__((ext_vector_type(8))) short short8;
typedef __attribute__((ext_vector_type(4))) float floatx4;

// ---------------------------------------------------------------------------
// Kernel 1: pure streaming x fp32 -> bf16. No scan, no serial chain, no
// warm-up re-reads. 2048 blocks grid-stride x8, 32B in / 16B out per iter.
// ---------------------------------------------------------------------------
__device__ __forceinline__ uint4 pack8_bf16(float4 a, float4 b) {
  union { unsigned short u[8]; uint4 q; } pk;
  __hip_bfloat16 t;
  t = __float2bfloat16(a.x); pk.u[0] = *(unsigned short*)&t;
  t = __float2bfloat16(a.y); pk.u[1] = *(unsigned short*)&t;
  t = __float2bfloat16(a.z); pk.u[2] = *(unsigned short*)&t;
  t = __float2bfloat16(a.w); pk.u[3] = *(unsigned short*)&t;
  t = __float2bfloat16(b.x); pk.u[4] = *(unsigned short*)&t;
  t = __float2bfloat16(b.y); pk.u[5] = *(unsigned short*)&t;
  t = __float2bfloat16(b.z); pk.u[6] = *(unsigned short*)&t;
  t = __float2bfloat16(b.w); pk.u[7] = *(unsigned short*)&t;
  return pk.q;
}

__global__ __launch_bounds__(256) void conv_x_kernel(
    const float* __restrict__ x, __hip_bfloat16* __restrict__ xs) {
  const size_t stride = 2048u * 256u;
  size_t t = (size_t)blockIdx.x * 256 + threadIdx.x;
  #pragma unroll
  for (int it = 0; it < 8; ++it, t += stride) {
    float4 v0 = *(const float4*)(x + t * 8);
    float4 v1 = *(const float4*)(x + t * 8 + 4);
    *(uint4*)(xs + t * 8) = pack8_bf16(v0, v1);
  }
}

// ---------------------------------------------------------------------------
// Kernel 2: W fp32 -> bf16, vectorized (1M elements).
// ---------------------------------------------------------------------------
__global__ __launch_bounds__(256) void conv_w_kernel(
    const float* __restrict__ W, __hip_bfloat16* __restrict__ Wb) {
  const size_t t = (size_t)blockIdx.x * 256 + threadIdx.x;
  float4 v0 = *(const float4*)(W + t * 8);
  float4 v1 = *(const float4*)(W + t * 8 + 4);
  *(uint4*)(Wb + t * 8) = pack8_bf16(v0, v1);
}

// ---------------------------------------------------------------------------
// Kernel 3: warm-up rows wx[tile][k] = sum_{j=1..16} 0.5^j x[b, s0-j, k].
// h(s0-1) = wx @ W^T by linearity; 0.5^16 truncation error ~1.5e-5.
// One block per m-tile (256), coalesced 4KB reads per j.
// ---------------------------------------------------------------------------
__global__ __launch_bounds__(256) void wx_kernel(
    const float* __restrict__ x, __hip_bfloat16* __restrict__ wx) {
  const int t = blockIdx.x;       // tile 0..255
  const int b = t >> 2;
  const int c = t & 3;            // s0 = c*128
  const int k4 = threadIdx.x * 4;
  float4 acc = {0.f, 0.f, 0.f, 0.f};
  if (c != 0) {
    const float* base = x + ((size_t)b * S_DIM + c * 128) * K_DIM + k4;
    float wgt = 0.5f;
    #pragma unroll
    for (int j = 1; j <= 16; ++j) {
      float4 v = *(const float4*)(base - (size_t)j * K_DIM);
      acc.x += wgt * v.x; acc.y += wgt * v.y;
      acc.z += wgt * v.z; acc.w += wgt * v.w;
      wgt *= 0.5f;
    }
  }
  union { unsigned short u[4]; uint2 q; } pk;
  __hip_bfloat16 h;
  h = __float2bfloat16(acc.x); pk.u[0] = *(unsigned short*)&h;
  h = __float2bfloat16(acc.y); pk.u[1] = *(unsigned short*)&h;
  h = __float2bfloat16(acc.z); pk.u[2] = *(unsigned short*)&h;
  h = __float2bfloat16(acc.w); pk.u[3] = *(unsigned short*)&h;
  *(uint2*)(wx + (size_t)t * K_DIM + k4) = pk.q;
}

// ---------------------------------------------------------------------------
// Kernel 4: bf16 NT GEMM, 128x128 tile, BK=64, 4 waves of 64x64 (unchanged
// K-loop: XCD swizzle + LDS k-slot swizzle + global_load_lds width-16).
//
// MAIN=true (grid 2048): fused EMA-scan epilogue. The scan h_s = 0.5 h_{s-1}
// + 0.5 y_s is linear, and each block's 128 m-rows are 128 consecutive s of
// one batch. Per column (fixed l15,j): lane-local 4-row scan L[r], then a
// decay-weighted Kogge-Stone prefix across quads (2 shfl_up, decay 0.5^4 /
// 0.5^8), fragment chain with decay 0.5^16, warm-up init from wy, and one
// LDS handoff (wm=0 -> wm=64 waves) applied as linear correction
// +0.5^(r+1)*h63. ~zero cost vs the 113us GEMM.
//
// MAIN=false (grid 16): same K-loop on wx[256,K] -> plain fp32 y = wy
// (warm-up states for the main epilogue).
// ---------------------------------------------------------------------------
template <bool MAIN>
__global__ __launch_bounds__(256) void gemm_tmpl(
    const __hip_bfloat16* __restrict__ A,   // [M, K]
    const __hip_bfloat16* __restrict__ Bw,  // [N, K]
    float* __restrict__ out,
    const float* __restrict__ warm) {       // wy [256, N] (MAIN only)
  __shared__ __hip_bfloat16 lA[128 * 64];   // 16 KB
  __shared__ __hip_bfloat16 lB[128 * 64];   // 16 KB
  __shared__ float hbuf[128];               // scan handoff (MAIN)

  const int tid  = threadIdx.x;
  const int lane = tid & 63;
  const int w    = tid >> 6;        // wave 0..3
  const int wm   = (w >> 1) * 64;   // wave m offset
  const int wn   = (w & 1) * 64;    // wave n offset
  const int quad = lane >> 4;       // 0..3
  const int l15  = lane & 15;
  const int r7   = l15 & 7;

  int m0, n0;
  if (MAIN) {
    const int bi    = blockIdx.x;   // 0..2047
    const int xcd   = bi & 7;
    const int local = bi >> 3;      // 0..255
    m0 = (xcd * 32 + (local >> 3)) * 128;
    n0 = (local & 7) * 128;
  } else {
    m0 = (blockIdx.x >> 3) * 128;   // 0..1
    n0 = (blockIdx.x & 7) * 128;
  }

  floatx4 acc[4][4] = {};

  for (int k0 = 0; k0 < K_DIM; k0 += 64) {
    #pragma unroll
    for (int p = 0; p < 4; ++p) {
      int c    = tid + p * 256;
      int r    = c >> 3;
      int slot = c & 7;
      int kc   = (slot ^ (r & 7)) * 8;
      const __hip_bfloat16* ga = A  + (size_t)(m0 + r) * K_DIM + k0 + kc;
      const __hip_bfloat16* gb = Bw + (size_t)(n0 + r) * K_DIM + k0 + kc;
      __builtin_amdgcn_global_load_lds(
          (const __attribute__((address_space(1))) void*)ga,
          (__attribute__((address_space(3))) void*)&lA[c * 8], 16, 0, 0);
      __builtin_amdgcn_global_load_lds(
          (const __attribute__((address_space(1))) void*)gb,
          (__attribute__((address_space(3))) void*)&lB[c * 8], 16, 0, 0);
    }
    __syncthreads();

    #pragma unroll
    for (int kk = 0; kk < 64; kk += 32) {
      const int q0 = kk >> 3;
      short8 af[4], bfr[4];
      #pragma unroll
      for (int i = 0; i < 4; ++i) {
        af[i]  = *(const short8*)&lA[(wm + i * 16 + l15) * 64 +
                                     (((q0 + quad) ^ r7) * 8)];
        bfr[i] = *(const short8*)&lB[(wn + i * 16 + l15) * 64 +
                                     (((q0 + quad) ^ r7) * 8)];
      }
      #pragma unroll
      for (int i = 0; i < 4; ++i)
        #pragma unroll
        for (int j = 0; j < 4; ++j)
          acc[i][j] = __builtin_amdgcn_mfma_f32_16x16x32_bf16(
              af[i], bfr[j], acc[i][j], 0, 0, 0);
    }
    __syncthreads();
  }

  // C/D layout: col = l15 (n), row = quad*4 + reg (m)  [m89-verified]
  if (MAIN) {
    // ---- fused EMA scan over the wave's 64 rows, per column ----
    const float fq = (quad == 0) ? 1.f : (quad == 1) ? 0.0625f
                   : (quad == 2) ? 0.00390625f : 2.44140625e-4f;  // 0.5^(4q)
    const int tile = m0 >> 7;
    #pragma unroll
    for (int j = 0; j < 4; ++j) {
      const int colIdx = wn + j * 16 + l15;
      float Wst = 0.f;                      // state before this wave's rows
      if (w < 2) Wst = warm[(size_t)tile * N_DIM + n0 + colIdx];
      #pragma unroll
      for (int i = 0; i < 4; ++i) {
        const float y0 = acc[i][j][0], y1 = acc[i][j][1];
        const float y2 = acc[i][j][2], y3 = acc[i][j][3];
        const float L0 = 0.5f * y0;         // local scan, zero init
        const float L1 = 0.5f * (L0 + y1);
        const float L2 = 0.5f * (L1 + y2);
        const float L3 = 0.5f * (L2 + y3);
        float P = L3;                       // KS prefix w/ decay 0.5^4
        float t1 = __shfl_up(P, 16);
        if (quad >= 1) P += 0.0625f * t1;
        float t2 = __shfl_up(P, 32);
        if (quad >= 2) P += 0.00390625f * t2;
        float H = __shfl_up(P, 16);         // state from quads < q
        H = (quad >= 1) ? H : 0.f;
        const float S = H + fq * Wst;       // state before row (i,q,0)
        acc[i][j][0] = L0 + 0.5f    * S;
        acc[i][j][1] = L1 + 0.25f   * S;
        acc[i][j][2] = L2 + 0.125f  * S;
        acc[i][j][3] = L3 + 0.0625f * S;
        const float F = __shfl(P, 48 + l15);          // fragment-total
        Wst = F + 1.52587890625e-05f * Wst;           // + 0.5^16 * prev
      }
      if (w < 2 && quad == 0) hbuf[colIdx] = Wst;     // h at row 63
    }
    __syncthreads();
    if (w >= 2) {  // linear correction: + 0.5^(r+1) * h63 (r = row in half)
      #pragma unroll
      for (int j = 0; j < 4; ++j) {
        const float Z = hbuf[wn + j * 16 + l15] * fq;
        #pragma unroll
        for (int i = 0; i < 4; ++i) {
          const float fi = (i == 0) ? 1.f
                         : (i == 1) ? 1.52587890625e-05f        // 0.5^16
                         : (i == 2) ? 2.3283064365386963e-10f   // 0.5^32
                                    : 3.552713678800501e-15f;   // 0.5^48
          const float base = fi * Z;
          acc[i][j][0] += 0.5f    * base;
          acc[i][j][1] += 0.25f   * base;
          acc[i][j][2] += 0.125f  * base;
          acc[i][j][3] += 0.0625f * base;
        }
      }
    }
  }

  float* hid = MAIN ? out + B_DIM * N_DIM : out;
  #pragma unroll
  for (int i = 0; i < 4; ++i) {
    #pragma unroll
    for (int j = 0; j < 4; ++j) {
      #pragma unroll
      for (int r = 0; r < 4; ++r) {
        int gm = m0 + wm + i * 16 + quad * 4 + r;
        int gn = n0 + wn + j * 16 + l15;
        float v = acc[i][j][r];
        hid[(size_t)gm * N_DIM + gn] = v;
        if (MAIN && ((gm & (S_DIM - 1)) == (S_DIM - 1))) {
          out[(size_t)(gm >> 9) * N_DIM + gn] = v;    // hk[b, n]
        }
      }
    }
  }
}

extern "C" void kernel_launch(void* const* d_in, const int* in_sizes, int n_in,
                              void* d_out, int out_size, void* d_ws, size_t ws_size,
                              hipStream_t stream) {
  const float* x = (const float*)d_in[0];   // [64, 512, 1024] fp32
  const float* W = (const float*)d_in[1];   // [1024, 1024] fp32
  float* out = (float*)d_out;               // [65536 hk][33.55M hiddens] fp32

  __hip_bfloat16* xs = (__hip_bfloat16*)d_ws;                 // 64 MB
  __hip_bfloat16* Wb = xs + (size_t)M_DIM * K_DIM;            // 2 MB
  __hip_bfloat16* wx = Wb + (size_t)N_DIM * K_DIM;            // 0.5 MB
  float*          wy = (float*)(wx + (size_t)N_TILES * K_DIM); // 1 MB

  conv_x_kernel<<<dim3(2048), dim3(256), 0, stream>>>(x, xs);
  conv_w_kernel<<<dim3((N_DIM * K_DIM) / (256 * 8)), dim3(256), 0, stream>>>(W, Wb);
  wx_kernel<<<dim3(N_TILES), dim3(256), 0, stream>>>(x, wx);
  gemm_tmpl<false><<<dim3(16), dim3(256), 0, stream>>>(wx, Wb, wy, nullptr);
  gemm_tmpl<true><<<dim3((M_DIM / 128) * (N_DIM / 128)), dim3(256), 0, stream>>>(xs, Wb, out, wy);
}